// Round 1
// baseline (2059.430 us; speedup 1.0000x reference)
//
#include <hip/hip_runtime.h>
#include <cstdint>
#include <cstddef>

// Problem constants: B=16, T=4096, D_IN=H=512, L=2, 3H=1536
#define BB 16
#define TT 4096
#define DD 512
#define NG 1536

typedef __bf16 bf16x8 __attribute__((ext_vector_type(8)));
typedef float f32x4 __attribute__((ext_vector_type(4)));

__device__ __forceinline__ unsigned short f2bf(float f) {
  union { float f; unsigned u; } v; v.f = f;
  return (unsigned short)((v.u + 0x7FFFu + ((v.u >> 16) & 1u)) >> 16);
}
__device__ __forceinline__ float bf2f(unsigned short s) {
  union { unsigned u; float f; } v; v.u = ((unsigned)s) << 16;
  return v.f;
}

// gates[m][n] = bias[n] + sum_k A[m][k] * W[n][k]
// A: fp32 [M x 512] (M = B*T), W: fp32 [1536 x 512], out: bf16 [M x 1536]
// 128x128 tile, BK=32, 256 threads = 4 waves (2x2), each wave 64x64 via 4x4
// fragments of mfma_f32_16x16x32_bf16.
__global__ __launch_bounds__(256) void gemm_gates(
    const float* __restrict__ A, const float* __restrict__ W,
    const float* __restrict__ bias, unsigned short* __restrict__ out)
{
  __shared__ __align__(16) unsigned short As[128 * 32];
  __shared__ __align__(16) unsigned short Bs[128 * 32];

  const int bn = blockIdx.x;        // 0..11  (N tiles) — x-fastest so blocks
  const int bm = blockIdx.y;        // 0..511 (M tiles)  sharing A run close
  const int tid = threadIdx.x;
  const int lane = tid & 63;
  const int wid = tid >> 6;
  const int wm = wid >> 1;          // 0..1
  const int wn = wid & 1;           // 0..1

  const long mBase = (long)bm * 128;
  const int  nBase = bn * 128;

  // staging: thread t loads row = t>>1, 16 fp32 at col (t&1)*16 of the K-chunk
  const int sRow = tid >> 1;
  const int sCol = (tid & 1) * 16;

  const int laneM = lane & 15;
  const int kOff  = (lane >> 4) * 8;

  f32x4 acc[4][4] = {};

  for (int k0 = 0; k0 < DD; k0 += 32) {
    const float* aSrc = A + (mBase + sRow) * DD + (k0 + sCol);
    const float* bSrc = W + (long)(nBase + sRow) * DD + (k0 + sCol);
    float4 av[4], bv[4];
#pragma unroll
    for (int i = 0; i < 4; ++i) {
      av[i] = *reinterpret_cast<const float4*>(aSrc + 4 * i);
      bv[i] = *reinterpret_cast<const float4*>(bSrc + 4 * i);
    }
    unsigned pa[8], pb[8];
#pragma unroll
    for (int i = 0; i < 4; ++i) {
      pa[2*i]   = (unsigned)f2bf(av[i].x) | ((unsigned)f2bf(av[i].y) << 16);
      pa[2*i+1] = (unsigned)f2bf(av[i].z) | ((unsigned)f2bf(av[i].w) << 16);
      pb[2*i]   = (unsigned)f2bf(bv[i].x) | ((unsigned)f2bf(bv[i].y) << 16);
      pb[2*i+1] = (unsigned)f2bf(bv[i].z) | ((unsigned)f2bf(bv[i].w) << 16);
    }
    __syncthreads();   // previous iteration's LDS reads done
    {
      uint4* adst = reinterpret_cast<uint4*>(&As[sRow * 32 + sCol]);
      adst[0] = make_uint4(pa[0], pa[1], pa[2], pa[3]);
      adst[1] = make_uint4(pa[4], pa[5], pa[6], pa[7]);
      uint4* bdst = reinterpret_cast<uint4*>(&Bs[sRow * 32 + sCol]);
      bdst[0] = make_uint4(pb[0], pb[1], pb[2], pb[3]);
      bdst[1] = make_uint4(pb[4], pb[5], pb[6], pb[7]);
    }
    __syncthreads();

    bf16x8 af[4], bfr[4];
#pragma unroll
    for (int mi = 0; mi < 4; ++mi)
      af[mi] = *reinterpret_cast<const bf16x8*>(
          &As[(wm * 64 + mi * 16 + laneM) * 32 + kOff]);
#pragma unroll
    for (int ni = 0; ni < 4; ++ni)
      bfr[ni] = *reinterpret_cast<const bf16x8*>(
          &Bs[(wn * 64 + ni * 16 + laneM) * 32 + kOff]);
#pragma unroll
    for (int mi = 0; mi < 4; ++mi)
#pragma unroll
      for (int ni = 0; ni < 4; ++ni)
        acc[mi][ni] = __builtin_amdgcn_mfma_f32_16x16x32_bf16(
            af[mi], bfr[ni], acc[mi][ni], 0, 0, 0);
  }

  // epilogue: D row=(lane>>4)*4+r (M-dim), col=lane&15 (N-dim)  [m89/m91]
  const int rowGrp = (lane >> 4) * 4;
#pragma unroll
  for (int ni = 0; ni < 4; ++ni) {
    const int n = nBase + wn * 64 + ni * 16 + laneM;
    const float bval = bias[n];
#pragma unroll
    for (int mi = 0; mi < 4; ++mi) {
      const long m = mBase + wm * 64 + mi * 16 + rowGrp;
#pragma unroll
      for (int r = 0; r < 4; ++r)
        out[(m + r) * (long)NG + n] = f2bf(acc[mi][ni][r] + bval);
    }
  }
}

// Sequential forget-mult scan. One thread per (b, h) chain: 8192 threads.
// gates: bf16 [B*T, 1536] (Z | F | O). Writes x = sigmoid(O)*C (fp32) and
// the final cell state into hout[b, layer, h].
__global__ __launch_bounds__(64) void qrnn_scan(
    const unsigned short* __restrict__ gates,
    const float* __restrict__ h0,    // [B, 2, 512]
    const int layer,
    float* __restrict__ xout,        // [B*T, 512]
    float* __restrict__ hout)        // [B, 2, 512]
{
  const int tid = blockIdx.x * blockDim.x + threadIdx.x;  // 0..8191
  const int b = tid >> 9;
  const int h = tid & 511;

  float c = h0[b * 1024 + layer * 512 + h];
  const unsigned short* g = gates + (size_t)b * TT * NG + h;
  float* xo = xout + (size_t)b * TT * DD + h;

  for (int t = 0; t < TT; t += 8) {
    unsigned short zr[8], fr[8], og[8];
#pragma unroll
    for (int u = 0; u < 8; ++u) {
      const unsigned short* gt = g + (size_t)(t + u) * NG;
      zr[u] = gt[0];
      fr[u] = gt[512];
      og[u] = gt[1024];
    }
#pragma unroll
    for (int u = 0; u < 8; ++u) {
      float z = bf2f(zr[u]);
      z = z > 0.f ? z : 0.f;
      const float f = 1.f / (1.f + __expf(-bf2f(fr[u])));
      const float o = 1.f / (1.f + __expf(-bf2f(og[u])));
      c = f * c + (1.f - f) * z;
      xo[(size_t)(t + u) * DD] = o * c;
    }
  }
  hout[b * 1024 + layer * 512 + h] = c;
}

extern "C" void kernel_launch(void* const* d_in, const int* in_sizes, int n_in,
                              void* d_out, int out_size, void* d_ws, size_t ws_size,
                              hipStream_t stream) {
  const float* x  = (const float*)d_in[0];
  const float* h0 = (const float*)d_in[1];
  const float* W0 = (const float*)d_in[2];
  const float* b0 = (const float*)d_in[3];
  const float* W1 = (const float*)d_in[4];
  const float* b1 = (const float*)d_in[5];

  float* out_x = (float*)d_out;                       // [B*T, 512]
  float* out_h = out_x + (size_t)BB * TT * DD;        // [B, 2, 512]
  unsigned short* gates = (unsigned short*)d_ws;      // bf16 [B*T, 1536]

  dim3 gemmGrid(NG / 128, (BB * TT) / 128);           // (12, 512)
  dim3 gemmBlk(256);
  dim3 scanGrid((BB * DD) / 64);                      // 128 blocks
  dim3 scanBlk(64);

  // Layer 0
  gemm_gates<<<gemmGrid, gemmBlk, 0, stream>>>(x, W0, b0, gates);
  qrnn_scan<<<scanGrid, scanBlk, 0, stream>>>(gates, h0, 0, out_x, out_h);
  // Layer 1 (input = layer-0 x output, read fully by GEMM before scan rewrites)
  gemm_gates<<<gemmGrid, gemmBlk, 0, stream>>>(out_x, W1, b1, gates);
  qrnn_scan<<<scanGrid, scanBlk, 0, stream>>>(gates, h0, 1, out_x, out_h);
}

// Round 2
// 728.143 us; speedup vs baseline: 2.8283x; 2.8283x over previous
//
#include <hip/hip_runtime.h>
#include <cstdint>
#include <cstddef>

// Problem constants: B=16, T=4096, D_IN=H=512, L=2, 3H=1536
#define BB 16
#define TT 4096
#define DD 512
#define NG 1536
#define NCH 64          // chunks per chain
#define CS  (TT / NCH)  // 64 timesteps per chunk
#define NCHAIN (BB * DD)  // 8192 chains

typedef __bf16 bf16x8 __attribute__((ext_vector_type(8)));
typedef float f32x4 __attribute__((ext_vector_type(4)));

__device__ __forceinline__ unsigned short f2bf(float f) {
  union { float f; unsigned u; } v; v.f = f;
  return (unsigned short)((v.u + 0x7FFFu + ((v.u >> 16) & 1u)) >> 16);
}
__device__ __forceinline__ float bf2f(unsigned short s) {
  union { unsigned u; float f; } v; v.u = ((unsigned)s) << 16;
  return v.f;
}
__device__ __forceinline__ float sigm(float x) {
  return 1.f / (1.f + __expf(-x));
}

// ---------------------------------------------------------------------------
// GEMM: gates[m][n] = bias[n] + sum_k A[m][k] * W[n][k]
// A: fp32 [M x 512] (M = B*T), W: fp32 [1536 x 512], out: bf16 [M x 1536]
// 128x128 tile, BK=32, 256 threads = 4 waves (2x2), each wave 64x64 via 4x4
// fragments of mfma_f32_16x16x32_bf16.
// ---------------------------------------------------------------------------
__global__ __launch_bounds__(256) void gemm_gates(
    const float* __restrict__ A, const float* __restrict__ W,
    const float* __restrict__ bias, unsigned short* __restrict__ out)
{
  __shared__ __align__(16) unsigned short As[128 * 32];
  __shared__ __align__(16) unsigned short Bs[128 * 32];

  const int bn = blockIdx.x;        // 0..11  (N tiles)
  const int bm = blockIdx.y;        // 0..511 (M tiles)
  const int tid = threadIdx.x;
  const int lane = tid & 63;
  const int wid = tid >> 6;
  const int wm = wid >> 1;          // 0..1
  const int wn = wid & 1;           // 0..1

  const long mBase = (long)bm * 128;
  const int  nBase = bn * 128;

  const int sRow = tid >> 1;
  const int sCol = (tid & 1) * 16;

  const int laneM = lane & 15;
  const int kOff  = (lane >> 4) * 8;

  f32x4 acc[4][4] = {};

  for (int k0 = 0; k0 < DD; k0 += 32) {
    const float* aSrc = A + (mBase + sRow) * DD + (k0 + sCol);
    const float* bSrc = W + (long)(nBase + sRow) * DD + (k0 + sCol);
    float4 av[4], bv[4];
#pragma unroll
    for (int i = 0; i < 4; ++i) {
      av[i] = *reinterpret_cast<const float4*>(aSrc + 4 * i);
      bv[i] = *reinterpret_cast<const float4*>(bSrc + 4 * i);
    }
    unsigned pa[8], pb[8];
#pragma unroll
    for (int i = 0; i < 4; ++i) {
      pa[2*i]   = (unsigned)f2bf(av[i].x) | ((unsigned)f2bf(av[i].y) << 16);
      pa[2*i+1] = (unsigned)f2bf(av[i].z) | ((unsigned)f2bf(av[i].w) << 16);
      pb[2*i]   = (unsigned)f2bf(bv[i].x) | ((unsigned)f2bf(bv[i].y) << 16);
      pb[2*i+1] = (unsigned)f2bf(bv[i].z) | ((unsigned)f2bf(bv[i].w) << 16);
    }
    __syncthreads();   // previous iteration's LDS reads done
    {
      uint4* adst = reinterpret_cast<uint4*>(&As[sRow * 32 + sCol]);
      adst[0] = make_uint4(pa[0], pa[1], pa[2], pa[3]);
      adst[1] = make_uint4(pa[4], pa[5], pa[6], pa[7]);
      uint4* bdst = reinterpret_cast<uint4*>(&Bs[sRow * 32 + sCol]);
      bdst[0] = make_uint4(pb[0], pb[1], pb[2], pb[3]);
      bdst[1] = make_uint4(pb[4], pb[5], pb[6], pb[7]);
    }
    __syncthreads();

    bf16x8 af[4], bfr[4];
#pragma unroll
    for (int mi = 0; mi < 4; ++mi)
      af[mi] = *reinterpret_cast<const bf16x8*>(
          &As[(wm * 64 + mi * 16 + laneM) * 32 + kOff]);
#pragma unroll
    for (int ni = 0; ni < 4; ++ni)
      bfr[ni] = *reinterpret_cast<const bf16x8*>(
          &Bs[(wn * 64 + ni * 16 + laneM) * 32 + kOff]);
#pragma unroll
    for (int mi = 0; mi < 4; ++mi)
#pragma unroll
      for (int ni = 0; ni < 4; ++ni)
        acc[mi][ni] = __builtin_amdgcn_mfma_f32_16x16x32_bf16(
            af[mi], bfr[ni], acc[mi][ni], 0, 0, 0);
  }

  // epilogue: D row=(lane>>4)*4+r (M-dim), col=lane&15 (N-dim)  [m89/m91]
  const int rowGrp = (lane >> 4) * 4;
#pragma unroll
  for (int ni = 0; ni < 4; ++ni) {
    const int n = nBase + wn * 64 + ni * 16 + laneM;
    const float bval = bias[n];
#pragma unroll
    for (int mi = 0; mi < 4; ++mi) {
      const long m = mBase + wm * 64 + mi * 16 + rowGrp;
#pragma unroll
      for (int r = 0; r < 4; ++r)
        out[(m + r) * (long)NG + n] = f2bf(acc[mi][ni][r] + bval);
    }
  }
}

// ---------------------------------------------------------------------------
// Chunked parallel scan. c_t = f_t*c_{t-1} + (1-f_t)*z_t is linear:
// over a segment, c_end = A*c_start + B with (A,B) <- (f*A, f*B + (1-f)*z).
// ---------------------------------------------------------------------------

// Phase 1: per (chain, chunk) compute segment transfer (A, B).
// thread tid: chain = tid & 8191 (coalesced h), chunk k = tid >> 13.
__global__ __launch_bounds__(256) void scan_phase1(
    const unsigned short* __restrict__ gates,
    float* __restrict__ Aout, float* __restrict__ Bout)
{
  const int tid = blockIdx.x * 256 + threadIdx.x;   // 0 .. NCHAIN*NCH-1
  const int chain = tid & (NCHAIN - 1);
  const int k = tid >> 13;
  const int b = chain >> 9;
  const int h = chain & 511;

  const unsigned short* g = gates + ((size_t)b * TT + (size_t)k * CS) * NG + h;

  float Ac = 1.f, Bc = 0.f;
  for (int t = 0; t < CS; t += 8) {
    unsigned short zr[8], fr[8];
#pragma unroll
    for (int u = 0; u < 8; ++u) {
      const unsigned short* gt = g + (size_t)(t + u) * NG;
      zr[u] = gt[0];
      fr[u] = gt[512];
    }
#pragma unroll
    for (int u = 0; u < 8; ++u) {
      float z = bf2f(zr[u]);
      z = z > 0.f ? z : 0.f;
      const float f = sigm(bf2f(fr[u]));
      Ac = f * Ac;
      Bc = f * Bc + (1.f - f) * z;
    }
  }
  Aout[(size_t)k * NCHAIN + chain] = Ac;
  Bout[(size_t)k * NCHAIN + chain] = Bc;
}

// Phase 2: per chain, sequential scan over NCH chunk transfers.
// Stores the chunk-start cell value for every chunk + the final h.
__global__ __launch_bounds__(256) void scan_phase2(
    const float* __restrict__ Ain, const float* __restrict__ Bin,
    const float* __restrict__ h0, const int layer,
    float* __restrict__ cstart, float* __restrict__ hout)
{
  const int chain = blockIdx.x * 256 + threadIdx.x;  // 0..8191
  const int b = chain >> 9;
  const int h = chain & 511;

  float c = h0[b * 1024 + layer * 512 + h];
#pragma unroll 8
  for (int k = 0; k < NCH; ++k) {
    cstart[(size_t)k * NCHAIN + chain] = c;
    c = Ain[(size_t)k * NCHAIN + chain] * c + Bin[(size_t)k * NCHAIN + chain];
  }
  hout[b * 1024 + layer * 512 + h] = c;
}

// Phase 3: per (chain, chunk) replay the chunk from its known start value,
// producing x = sigmoid(O) * C.
__global__ __launch_bounds__(256) void scan_phase3(
    const unsigned short* __restrict__ gates,
    const float* __restrict__ cstart,
    float* __restrict__ xout)
{
  const int tid = blockIdx.x * 256 + threadIdx.x;
  const int chain = tid & (NCHAIN - 1);
  const int k = tid >> 13;
  const int b = chain >> 9;
  const int h = chain & 511;

  const unsigned short* g = gates + ((size_t)b * TT + (size_t)k * CS) * NG + h;
  float* xo = xout + ((size_t)b * TT + (size_t)k * CS) * DD + h;

  float c = cstart[(size_t)k * NCHAIN + chain];
  for (int t = 0; t < CS; t += 8) {
    unsigned short zr[8], fr[8], og[8];
#pragma unroll
    for (int u = 0; u < 8; ++u) {
      const unsigned short* gt = g + (size_t)(t + u) * NG;
      zr[u] = gt[0];
      fr[u] = gt[512];
      og[u] = gt[1024];
    }
#pragma unroll
    for (int u = 0; u < 8; ++u) {
      float z = bf2f(zr[u]);
      z = z > 0.f ? z : 0.f;
      const float f = sigm(bf2f(fr[u]));
      const float o = sigm(bf2f(og[u]));
      c = f * c + (1.f - f) * z;
      xo[(size_t)(t + u) * DD] = o * c;
    }
  }
}

extern "C" void kernel_launch(void* const* d_in, const int* in_sizes, int n_in,
                              void* d_out, int out_size, void* d_ws, size_t ws_size,
                              hipStream_t stream) {
  const float* x  = (const float*)d_in[0];
  const float* h0 = (const float*)d_in[1];
  const float* W0 = (const float*)d_in[2];
  const float* b0 = (const float*)d_in[3];
  const float* W1 = (const float*)d_in[4];
  const float* b1 = (const float*)d_in[5];

  float* out_x = (float*)d_out;                       // [B*T, 512]
  float* out_h = out_x + (size_t)BB * TT * DD;        // [B, 2, 512]

  // workspace layout
  char* ws = (char*)d_ws;
  unsigned short* gates = (unsigned short*)ws;        // bf16 [B*T, 1536] = 201.3 MB
  size_t off = (size_t)BB * TT * NG * sizeof(unsigned short);
  float* Abuf   = (float*)(ws + off); off += (size_t)NCH * NCHAIN * sizeof(float); // 2 MB
  float* Bbuf   = (float*)(ws + off); off += (size_t)NCH * NCHAIN * sizeof(float); // 2 MB
  float* cstart = (float*)(ws + off);                                              // 2 MB

  dim3 gemmGrid(NG / 128, (BB * TT) / 128);           // (12, 512)
  dim3 gemmBlk(256);
  const int pThreads = NCHAIN * NCH;                  // 524288
  dim3 pGrid(pThreads / 256);
  dim3 pBlk(256);
  dim3 p2Grid(NCHAIN / 256);

  // Layer 0
  gemm_gates<<<gemmGrid, gemmBlk, 0, stream>>>(x, W0, b0, gates);
  scan_phase1<<<pGrid, pBlk, 0, stream>>>(gates, Abuf, Bbuf);
  scan_phase2<<<p2Grid, pBlk, 0, stream>>>(Abuf, Bbuf, h0, 0, cstart, out_h);
  scan_phase3<<<pGrid, pBlk, 0, stream>>>(gates, cstart, out_x);
  // Layer 1 (input = layer-0 x output, read fully by GEMM before scan rewrites)
  gemm_gates<<<gemmGrid, gemmBlk, 0, stream>>>(out_x, W1, b1, gates);
  scan_phase1<<<pGrid, pBlk, 0, stream>>>(gates, Abuf, Bbuf);
  scan_phase2<<<p2Grid, pBlk, 0, stream>>>(Abuf, Bbuf, h0, 1, cstart, out_h);
  scan_phase3<<<pGrid, pBlk, 0, stream>>>(gates, cstart, out_x);
}

// Round 3
// 562.166 us; speedup vs baseline: 3.6634x; 1.2952x over previous
//
#include <hip/hip_runtime.h>
#include <cstdint>
#include <cstddef>

// Problem constants: B=16, T=4096, D_IN=H=512, L=2, 3H=1536
#define BB 16
#define TT 4096
#define DD 512
#define NG 1536
#define BK 64
#define NCH 64            // chunks per chain
#define CS  (TT / NCH)    // 64 timesteps per chunk
#define NCHAIN (BB * DD)  // 8192 chains

typedef __bf16 bf16x8 __attribute__((ext_vector_type(8)));
typedef float f32x4 __attribute__((ext_vector_type(4)));

__device__ __forceinline__ unsigned short f2bf(float f) {
  union { float f; unsigned u; } v; v.f = f;
  return (unsigned short)((v.u + 0x7FFFu + ((v.u >> 16) & 1u)) >> 16);
}
__device__ __forceinline__ float bf2f(unsigned short s) {
  union { unsigned u; float f; } v; v.u = ((unsigned)s) << 16;
  return v.f;
}
__device__ __forceinline__ float sigm(float x) {
  return 1.f / (1.f + __expf(-x));
}

// async global->LDS, 16B per lane. LDS dest = wave-uniform base + lane*16.
__device__ __forceinline__ void gload_lds16(const void* g, void* l) {
  __builtin_amdgcn_global_load_lds(
      (const __attribute__((address_space(1))) unsigned*)g,
      (__attribute__((address_space(3))) unsigned*)l, 16, 0, 0);
}

// ---------------------------------------------------------------------------
// fp32 -> bf16 bulk convert (vectorized: 8 elems/thread/iter)
// ---------------------------------------------------------------------------
__global__ __launch_bounds__(256) void f32_to_bf16(
    const float* __restrict__ in, unsigned short* __restrict__ out, long n)
{
  const long stride = (long)gridDim.x * 256 * 8;
  for (long i = ((long)blockIdx.x * 256 + threadIdx.x) * 8; i < n; i += stride) {
    float4 a = *reinterpret_cast<const float4*>(in + i);
    float4 b = *reinterpret_cast<const float4*>(in + i + 4);
    uint4 p;
    p.x = (unsigned)f2bf(a.x) | ((unsigned)f2bf(a.y) << 16);
    p.y = (unsigned)f2bf(a.z) | ((unsigned)f2bf(a.w) << 16);
    p.z = (unsigned)f2bf(b.x) | ((unsigned)f2bf(b.y) << 16);
    p.w = (unsigned)f2bf(b.z) | ((unsigned)f2bf(b.w) << 16);
    *reinterpret_cast<uint4*>(out + i) = p;
  }
}

// ---------------------------------------------------------------------------
// GEMM (m97 structure): gates[m][n] = bias[n] + sum_k A[m][k] * W[n][k]
// A: bf16 [M x 512] (M = B*T), W: bf16 [1536 x 512] (B^T layout),
// out: bf16 [M x 1536]. 128x128 tile, BK=64, 256 thr = 4 waves (2x2),
// global_load_lds width-16 staging, linear LDS, 2-barrier K-loop.
// ---------------------------------------------------------------------------
__global__ __launch_bounds__(256) void gemm_bf16(
    const unsigned short* __restrict__ A, const unsigned short* __restrict__ W,
    const float* __restrict__ bias, unsigned short* __restrict__ out)
{
  __shared__ __align__(16) unsigned short As[128 * BK];
  __shared__ __align__(16) unsigned short Bs[128 * BK];

  // bijective XCD-chunked swizzle: nwg = 6144 (divisible by 8)
  const int cpx = gridDim.x >> 3;
  const int swz = (blockIdx.x & 7) * cpx + (blockIdx.x >> 3);
  const int bm = swz / 12;          // 0..511 (M tiles)
  const int bn = swz % 12;          // 0..11  (N tiles; adjacent swz share bm)

  const int tid = threadIdx.x;
  const int lane = tid & 63;
  const int wid = tid >> 6;
  const int wm = wid >> 1;          // 0..1
  const int wn = wid & 1;           // 0..1

  const long mBase = (long)bm * 128;
  const int  nBase = bn * 128;

  // staging: wave `wid` call j covers rows wid*32 + j*8 .. +7 (1KB per call).
  // lane l -> row_local = l>>3, col = (l&7)*8 bf16 (16B)
  const int sRow = lane >> 3;
  const int sCol = (lane & 7) * 8;

  const int laneM = lane & 15;
  const int kHi = (lane >> 4) * 8;

  f32x4 acc[4][4] = {};

  for (int k0 = 0; k0 < DD; k0 += BK) {
    __syncthreads();   // previous iteration's LDS reads done
#pragma unroll
    for (int j = 0; j < 4; ++j) {
      const int rbase = wid * 32 + j * 8;
      gload_lds16(A + (mBase + rbase + sRow) * DD + k0 + sCol,
                  &As[rbase * BK]);
      gload_lds16(W + (long)(nBase + rbase + sRow) * DD + k0 + sCol,
                  &Bs[rbase * BK]);
    }
    __syncthreads();   // drains vmcnt(0): staged tile visible

#pragma unroll
    for (int kk = 0; kk < 2; ++kk) {
      const int kOff = kk * 32 + kHi;
      bf16x8 af[4], bfr[4];
#pragma unroll
      for (int mi = 0; mi < 4; ++mi)
        af[mi] = *reinterpret_cast<const bf16x8*>(
            &As[(wm * 64 + mi * 16 + laneM) * BK + kOff]);
#pragma unroll
      for (int ni = 0; ni < 4; ++ni)
        bfr[ni] = *reinterpret_cast<const bf16x8*>(
            &Bs[(wn * 64 + ni * 16 + laneM) * BK + kOff]);
#pragma unroll
      for (int mi = 0; mi < 4; ++mi)
#pragma unroll
        for (int ni = 0; ni < 4; ++ni)
          acc[mi][ni] = __builtin_amdgcn_mfma_f32_16x16x32_bf16(
              af[mi], bfr[ni], acc[mi][ni], 0, 0, 0);
    }
  }

  // epilogue: D row=(lane>>4)*4+r (M-dim), col=lane&15 (N-dim)  [m89/m91]
  const int rowGrp = (lane >> 4) * 4;
#pragma unroll
  for (int ni = 0; ni < 4; ++ni) {
    const int n = nBase + wn * 64 + ni * 16 + laneM;
    const float bval = bias[n];
#pragma unroll
    for (int mi = 0; mi < 4; ++mi) {
      const long m = mBase + wm * 64 + mi * 16 + rowGrp;
#pragma unroll
      for (int r = 0; r < 4; ++r)
        out[(m + r) * (long)NG + n] = f2bf(acc[mi][ni][r] + bval);
    }
  }
}

// ---------------------------------------------------------------------------
// Chunked parallel scan. c_t = f_t*c_{t-1} + (1-f_t)*z_t is linear:
// over a segment, c_end = A*c_start + B with (A,B) <- (f*A, f*B + (1-f)*z).
// ---------------------------------------------------------------------------

// Phase 1: per (chain, chunk) compute segment transfer (A, B).
__global__ __launch_bounds__(256) void scan_phase1(
    const unsigned short* __restrict__ gates,
    float* __restrict__ Aout, float* __restrict__ Bout)
{
  const int tid = blockIdx.x * 256 + threadIdx.x;   // 0 .. NCHAIN*NCH-1
  const int chain = tid & (NCHAIN - 1);
  const int k = tid >> 13;
  const int b = chain >> 9;
  const int h = chain & 511;

  const unsigned short* g = gates + ((size_t)b * TT + (size_t)k * CS) * NG + h;

  float Ac = 1.f, Bc = 0.f;
  for (int t = 0; t < CS; t += 8) {
    unsigned short zr[8], fr[8];
#pragma unroll
    for (int u = 0; u < 8; ++u) {
      const unsigned short* gt = g + (size_t)(t + u) * NG;
      zr[u] = gt[0];
      fr[u] = gt[512];
    }
#pragma unroll
    for (int u = 0; u < 8; ++u) {
      float z = bf2f(zr[u]);
      z = z > 0.f ? z : 0.f;
      const float f = sigm(bf2f(fr[u]));
      Ac = f * Ac;
      Bc = f * Bc + (1.f - f) * z;
    }
  }
  Aout[(size_t)k * NCHAIN + chain] = Ac;
  Bout[(size_t)k * NCHAIN + chain] = Bc;
}

// Phase 2: per chain, sequential scan over NCH chunk transfers.
__global__ __launch_bounds__(256) void scan_phase2(
    const float* __restrict__ Ain, const float* __restrict__ Bin,
    const float* __restrict__ h0, const int layer,
    float* __restrict__ cstart, float* __restrict__ hout)
{
  const int chain = blockIdx.x * 256 + threadIdx.x;  // 0..8191
  const int b = chain >> 9;
  const int h = chain & 511;

  float c = h0[b * 1024 + layer * 512 + h];
#pragma unroll 8
  for (int k = 0; k < NCH; ++k) {
    cstart[(size_t)k * NCHAIN + chain] = c;
    c = Ain[(size_t)k * NCHAIN + chain] * c + Bin[(size_t)k * NCHAIN + chain];
  }
  hout[b * 1024 + layer * 512 + h] = c;
}

// Phase 3: per (chain, chunk) replay the chunk from its known start value,
// producing x = sigmoid(O) * C (fp32 to d_out; optional bf16 copy for the
// next layer's GEMM input).
template <bool WRITE_BF16>
__global__ __launch_bounds__(256) void scan_phase3(
    const unsigned short* __restrict__ gates,
    const float* __restrict__ cstart,
    float* __restrict__ xout,
    unsigned short* __restrict__ xb)
{
  const int tid = blockIdx.x * 256 + threadIdx.x;
  const int chain = tid & (NCHAIN - 1);
  const int k = tid >> 13;
  const int b = chain >> 9;
  const int h = chain & 511;

  const unsigned short* g = gates + ((size_t)b * TT + (size_t)k * CS) * NG + h;
  const size_t xoff = ((size_t)b * TT + (size_t)k * CS) * DD + h;
  float* xo = xout + xoff;
  unsigned short* xbo = xb + xoff;

  float c = cstart[(size_t)k * NCHAIN + chain];
  for (int t = 0; t < CS; t += 8) {
    unsigned short zr[8], fr[8], og[8];
#pragma unroll
    for (int u = 0; u < 8; ++u) {
      const unsigned short* gt = g + (size_t)(t + u) * NG;
      zr[u] = gt[0];
      fr[u] = gt[512];
      og[u] = gt[1024];
    }
#pragma unroll
    for (int u = 0; u < 8; ++u) {
      float z = bf2f(zr[u]);
      z = z > 0.f ? z : 0.f;
      const float f = sigm(bf2f(fr[u]));
      const float o = sigm(bf2f(og[u]));
      c = f * c + (1.f - f) * z;
      const float xv = o * c;
      xo[(size_t)(t + u) * DD] = xv;
      if (WRITE_BF16) xbo[(size_t)(t + u) * DD] = f2bf(xv);
    }
  }
}

extern "C" void kernel_launch(void* const* d_in, const int* in_sizes, int n_in,
                              void* d_out, int out_size, void* d_ws, size_t ws_size,
                              hipStream_t stream) {
  const float* x  = (const float*)d_in[0];
  const float* h0 = (const float*)d_in[1];
  const float* W0 = (const float*)d_in[2];
  const float* b0 = (const float*)d_in[3];
  const float* W1 = (const float*)d_in[4];
  const float* b1 = (const float*)d_in[5];

  float* out_x = (float*)d_out;                       // [B*T, 512]
  float* out_h = out_x + (size_t)BB * TT * DD;        // [B, 2, 512]

  // workspace layout (~278 MB)
  char* ws = (char*)d_ws;
  unsigned short* gates = (unsigned short*)ws;        // bf16 [B*T,1536] 201.3MB
  size_t off = (size_t)BB * TT * NG * 2;
  unsigned short* xb  = (unsigned short*)(ws + off);  // bf16 [B*T,512]  67.1MB
  off += (size_t)BB * TT * DD * 2;
  unsigned short* W0b = (unsigned short*)(ws + off);  // bf16 [1536,512] 1.5MB
  off += (size_t)NG * DD * 2;
  unsigned short* W1b = (unsigned short*)(ws + off);  // 1.5MB
  off += (size_t)NG * DD * 2;
  float* Abuf   = (float*)(ws + off); off += (size_t)NCH * NCHAIN * 4; // 2MB
  float* Bbuf   = (float*)(ws + off); off += (size_t)NCH * NCHAIN * 4; // 2MB
  float* cstart = (float*)(ws + off);                                  // 2MB

  dim3 blk(256);
  dim3 gemmGrid((NG / 128) * ((BB * TT) / 128));      // 6144
  dim3 pGrid((NCHAIN * NCH) / 256);                   // 2048
  dim3 p2Grid(NCHAIN / 256);                          // 32

  // input conversions (numerically identical to R2's in-kernel rounding)
  f32_to_bf16<<<2048, blk, 0, stream>>>(x, xb, (long)BB * TT * DD);
  f32_to_bf16<<<256, blk, 0, stream>>>(W0, W0b, (long)NG * DD);
  f32_to_bf16<<<256, blk, 0, stream>>>(W1, W1b, (long)NG * DD);

  // Layer 0
  gemm_bf16<<<gemmGrid, blk, 0, stream>>>(xb, W0b, b0, gates);
  scan_phase1<<<pGrid, blk, 0, stream>>>(gates, Abuf, Bbuf);
  scan_phase2<<<p2Grid, blk, 0, stream>>>(Abuf, Bbuf, h0, 0, cstart, out_h);
  scan_phase3<true><<<pGrid, blk, 0, stream>>>(gates, cstart, out_x, xb);
  // Layer 1 (xb rewritten by phase3 after gemm0 consumed it)
  gemm_bf16<<<gemmGrid, blk, 0, stream>>>(xb, W1b, b1, gates);
  scan_phase1<<<pGrid, blk, 0, stream>>>(gates, Abuf, Bbuf);
  scan_phase2<<<p2Grid, blk, 0, stream>>>(Abuf, Bbuf, h0, 1, cstart, out_h);
  scan_phase3<false><<<pGrid, blk, 0, stream>>>(gates, cstart, out_x, nullptr);
}